// Round 5
// baseline (638.291 us; speedup 1.0000x reference)
//
#include <hip/hip_runtime.h>
#include <hip/hip_bf16.h>
#include <math.h>

#define N_PATHS  200000
#define PATH_LEN 8
#define N_LINKS  20000
#define MAX_PL   100
#define DIM      16
#define ITERS    8

typedef __attribute__((ext_vector_type(8))) short bf16x8;
typedef __attribute__((ext_vector_type(4))) float f32x4;

// ws layout (bytes):
//   seq   : ushort[10][N_PATHS][16] = 64,000,000  (bf16 states; slots 1..7 = steps, 8/9 = prev/cur rotation)
//   ls    : float [N_LINKS][16]     =  1,280,000
//   lxk   : ushort[N_LINKS][48]     =  1,920,000
//   p2lpE : uint  [N_LINKS*MAX_PL]  =  8,000,000  (slot-resolved for even iters)
//   p2lpO : uint  [N_LINKS*MAX_PL]  =  8,000,000  (slot-resolved for odd iters)
#define SEQ_BYTES 64000000ull
#define LS_BYTES  1280000ull
#define LXK_BYTES 1920000ull
#define P2L_BYTES 8000000ull

__device__ __forceinline__ float fast_sigmoid(float x) {
    return __builtin_amdgcn_rcpf(1.0f + __expf(-x));
}
__device__ __forceinline__ float fast_tanh(float x) {
    float ax = fabsf(x);
    float t  = __expf(-2.0f * ax);
    float r  = (1.0f - t) * __builtin_amdgcn_rcpf(1.0f + t);
    return copysignf(r, x);
}
__device__ __forceinline__ float softplusf_(float x) {
    return fmaxf(x, 0.0f) + log1pf(expf(-fabsf(x)));
}
__device__ __forceinline__ float bflo(unsigned int u) {
    union { unsigned int i; float f; } c; c.i = u << 16; return c.f;
}
__device__ __forceinline__ float bfhi(unsigned int u) {
    union { unsigned int i; float f; } c; c.i = u & 0xffff0000u; return c.f;
}
__device__ __forceinline__ unsigned int pk_bf16(float lo, float hi) {
    unsigned int r;
    asm("v_cvt_pk_bf16_f32 %0, %1, %2" : "=v"(r) : "v"(lo), "v"(hi));
    return r;
}

union U8 { unsigned int u[4]; bf16x8 v; };

// ---------------- pack p2l into two slot-resolved variants ----------------
__global__ __launch_bounds__(256) void k_pack(const int* __restrict__ p2l,
                                              unsigned int* __restrict__ outE,
                                              unsigned int* __restrict__ outO)
{
    int i = blockIdx.x * 256 + threadIdx.x;
    if (i < N_LINKS * MAX_PL) {
        unsigned int pi = (unsigned int)p2l[2 * i];
        unsigned int si = (unsigned int)p2l[2 * i + 1];
        unsigned int sE = (si == 0) ? 8u : ((si == 8) ? 9u : si);
        unsigned int sO = (si == 0) ? 9u : ((si == 8) ? 8u : si);
        outE[i] = (sE << 18) | pi;
        outO[i] = (sO << 18) | pi;
    }
}

// ---------------- init: link load -> link_state -> lxk ----------------
__global__ __launch_bounds__(64) void k_init_links(
    const float* __restrict__ traffic, const float* __restrict__ cap,
    const int* __restrict__ p2l,
    const float* __restrict__ le_w1, const float* __restrict__ le_b1,
    const float* __restrict__ le_w2, const float* __restrict__ le_b2,
    const float* __restrict__ pk, const float* __restrict__ pb,
    float* __restrict__ ls, unsigned short* __restrict__ lxk)
{
    int l = blockIdx.x;
    int lane = threadIdx.x;
    float s = 0.0f;
    for (int j = lane; j < MAX_PL; j += 64) {
        int p = p2l[(size_t)(l * MAX_PL + j) * 2 + 0];
        s += traffic[p];
    }
    #pragma unroll
    for (int off = 32; off > 0; off >>= 1) s += __shfl_xor(s, off);

    float c = cap[l];
    float f0 = c * 0.1f;
    float f1 = s / (c * 1e9f);

    float h1[DIM];
    #pragma unroll
    for (int d = 0; d < DIM; d++)
        h1[d] = fmaxf(f0 * le_w1[d] + f1 * le_w1[DIM + d] + le_b1[d], 0.0f);

    float h2[DIM];
    #pragma unroll
    for (int d = 0; d < DIM; d++) {
        float a = le_b2[d];
        #pragma unroll
        for (int k = 0; k < DIM; k++) a = fmaf(h1[k], le_w2[k * DIM + d], a);
        h2[d] = fmaxf(a, 0.0f);
    }
    if (lane < DIM) ls[(size_t)l * DIM + lane] = h2[lane];
    if (lane < 48) {
        float a = pb[lane];
        #pragma unroll
        for (int k = 0; k < DIM; k++) a = fmaf(h2[k], pk[k * 48 + lane], a);
        lxk[(size_t)l * 48 + lane] = (unsigned short)(pk_bf16(a, a) & 0xffffu);
    }
}

// ---------------- init: path_state -> seq slot 8 (bf16) ----------------
__global__ __launch_bounds__(256) void k_init_paths(
    const float* __restrict__ traffic, const float* __restrict__ packets,
    const float* __restrict__ pktsize, const float* __restrict__ ftype,
    const float* __restrict__ fe_w1, const float* __restrict__ fe_b1,
    const float* __restrict__ fe_w2, const float* __restrict__ fe_b2,
    unsigned short* __restrict__ seq)
{
    int p = blockIdx.x * blockDim.x + threadIdx.x;
    if (p >= N_PATHS) return;
    float f[5];
    f[0] = traffic[p] * 0.0001f;
    f[1] = packets[p] * 0.01f;
    f[2] = pktsize[p] * 0.001f;
    f[3] = ftype[p * 2 + 0];
    f[4] = ftype[p * 2 + 1];

    float h1[DIM];
    #pragma unroll
    for (int d = 0; d < DIM; d++) {
        float a = fe_b1[d];
        #pragma unroll
        for (int k = 0; k < 5; k++) a = fmaf(f[k], fe_w1[k * DIM + d], a);
        h1[d] = fmaxf(a, 0.0f);
    }
    float h2[DIM];
    #pragma unroll
    for (int d = 0; d < DIM; d++) {
        float a = fe_b2[d];
        #pragma unroll
        for (int k = 0; k < DIM; k++) a = fmaf(h1[k], fe_w2[k * DIM + d], a);
        h2[d] = fmaxf(a, 0.0f);
    }
    unsigned int pkd[8];
    #pragma unroll
    for (int q = 0; q < 8; q++) pkd[q] = pk_bf16(h2[2 * q], h2[2 * q + 1]);
    uint4* out = (uint4*)(seq + ((size_t)8 * N_PATHS + p) * DIM);
    out[0] = make_uint4(pkd[0], pkd[1], pkd[2], pkd[3]);
    out[1] = make_uint4(pkd[4], pkd[5], pkd[6], pkd[7]);
}

// ---------------- per-iteration: path GRU via MFMA, 32 paths/wave (2 tiles) ----------------
// D/C layout (16x16x32_bf16): col=lane&15, row=(lane>>4)*4+reg.
// A/B split-K hedge: weights*0.5 duplicated in both halves, h in both B halves.
// Two independent recurrence chains per wave (tiles A,B) for ILP; rolling
// prefetch depth 4 of the lxk gathers.
__global__ __launch_bounds__(256) void k_paths(
    const int* __restrict__ l2p, const unsigned short* __restrict__ lxk,
    const float* __restrict__ rk, const float* __restrict__ b,
    unsigned short* __restrict__ seq, int ps, int cs)
{
    int l = threadIdx.x & 63;
    int wave = (blockIdx.x * 256 + threadIdx.x) >> 6;
    if (wave >= N_PATHS / 32) return;
    int pr = l & 15;
    int g  = l >> 4;
    int kq = g * 4;
    int pA = wave * 32 + pr;
    int pB = pA + 16;

    U8 Az, Ar, Ah;
    {
        #pragma unroll
        for (int i = 0; i < 2; i++) {
            float wz0 = rk[(kq + 2 * i) * 48 + pr] * 0.5f;
            float wz1 = rk[(kq + 2 * i + 1) * 48 + pr] * 0.5f;
            float wr0 = rk[(kq + 2 * i) * 48 + 16 + pr] * 0.5f;
            float wr1 = rk[(kq + 2 * i + 1) * 48 + 16 + pr] * 0.5f;
            float wh0 = rk[(kq + 2 * i) * 48 + 32 + pr] * 0.5f;
            float wh1 = rk[(kq + 2 * i + 1) * 48 + 32 + pr] * 0.5f;
            Az.u[i] = pk_bf16(wz0, wz1); Az.u[i + 2] = Az.u[i];
            Ar.u[i] = pk_bf16(wr0, wr1); Ar.u[i + 2] = Ar.u[i];
            Ah.u[i] = pk_bf16(wh0, wh1); Ah.u[i + 2] = Ah.u[i];
        }
    }
    f32x4 Cz, Cr, Ch;
    #pragma unroll
    for (int r = 0; r < 4; r++) {
        Cz[r] = b[48 + kq + r];
        Cr[r] = b[48 + 16 + kq + r];
        Ch[r] = b[48 + 32 + kq + r];
    }

    int2 iA = *(const int2*)(l2p + (size_t)pA * 8 + 2 * g);
    int2 iB = *(const int2*)(l2p + (size_t)pB * 8 + 2 * g);

    uint2 uzA[8], urA[8], uhA[8];
    uint2 uzB[8], urB[8], uhB[8];

#define PREF(t) { \
    int liA = __shfl(((t) & 1) ? iA.y : iA.x, pr + 16 * ((t) >> 1)); \
    const unsigned short* xa = lxk + (size_t)liA * 48 + kq; \
    uzA[t] = *(const uint2*)(xa); urA[t] = *(const uint2*)(xa + 16); uhA[t] = *(const uint2*)(xa + 32); \
    int liB = __shfl(((t) & 1) ? iB.y : iB.x, pr + 16 * ((t) >> 1)); \
    const unsigned short* xb = lxk + (size_t)liB * 48 + kq; \
    uzB[t] = *(const uint2*)(xb); urB[t] = *(const uint2*)(xb + 16); uhB[t] = *(const uint2*)(xb + 32); }

    PREF(0) PREF(1) PREF(2) PREF(3)

    float hA0, hA1, hA2, hA3, hB0, hB1, hB2, hB3;
    U8 BA, BB;
    {
        uint2 hp = *(const uint2*)(seq + ((size_t)ps * N_PATHS + pA) * DIM + kq);
        hA0 = bflo(hp.x); hA1 = bfhi(hp.x); hA2 = bflo(hp.y); hA3 = bfhi(hp.y);
        BA.u[0] = hp.x; BA.u[1] = hp.y; BA.u[2] = hp.x; BA.u[3] = hp.y;
        uint2 hq = *(const uint2*)(seq + ((size_t)ps * N_PATHS + pB) * DIM + kq);
        hB0 = bflo(hq.x); hB1 = bfhi(hq.x); hB2 = bflo(hq.y); hB3 = bfhi(hq.y);
        BB.u[0] = hq.x; BB.u[1] = hq.y; BB.u[2] = hq.x; BB.u[3] = hq.y;
    }

#define TCORE(t, os, uzX, urX, uhX, BX, h0X, h1X, h2X, h3X, pX) { \
    uint2 uz = uzX[t], ur = urX[t], uh = uhX[t]; \
    f32x4 az = __builtin_amdgcn_mfma_f32_16x16x32_bf16(Az.v, BX.v, Cz, 0, 0, 0); \
    f32x4 ar = __builtin_amdgcn_mfma_f32_16x16x32_bf16(Ar.v, BX.v, Cr, 0, 0, 0); \
    f32x4 ah = __builtin_amdgcn_mfma_f32_16x16x32_bf16(Ah.v, BX.v, Ch, 0, 0, 0); \
    float z0 = fast_sigmoid(bflo(uz.x) + az[0]), z1 = fast_sigmoid(bfhi(uz.x) + az[1]); \
    float z2 = fast_sigmoid(bflo(uz.y) + az[2]), z3 = fast_sigmoid(bfhi(uz.y) + az[3]); \
    float r0 = fast_sigmoid(bflo(ur.x) + ar[0]), r1 = fast_sigmoid(bfhi(ur.x) + ar[1]); \
    float r2 = fast_sigmoid(bflo(ur.y) + ar[2]), r3 = fast_sigmoid(bfhi(ur.y) + ar[3]); \
    float q0 = fast_tanh(bflo(uh.x) + r0 * ah[0]), q1 = fast_tanh(bfhi(uh.x) + r1 * ah[1]); \
    float q2 = fast_tanh(bflo(uh.y) + r2 * ah[2]), q3 = fast_tanh(bfhi(uh.y) + r3 * ah[3]); \
    h0X = z0 * h0X + (1.0f - z0) * q0; \
    h1X = z1 * h1X + (1.0f - z1) * q1; \
    h2X = z2 * h2X + (1.0f - z2) * q2; \
    h3X = z3 * h3X + (1.0f - z3) * q3; \
    unsigned int p01 = pk_bf16(h0X, h1X), p23 = pk_bf16(h2X, h3X); \
    *(uint2*)(seq + ((size_t)(os) * N_PATHS + pX) * DIM + kq) = make_uint2(p01, p23); \
    BX.u[0] = p01; BX.u[1] = p23; BX.u[2] = p01; BX.u[3] = p23; }

#define STEP(t, os) \
    TCORE(t, os, uzA, urA, uhA, BA, hA0, hA1, hA2, hA3, pA) \
    TCORE(t, os, uzB, urB, uhB, BB, hB0, hB1, hB2, hB3, pB)

    PREF(4) STEP(0, 1)
    PREF(5) STEP(1, 2)
    PREF(6) STEP(2, 3)
    PREF(7) STEP(3, 4)
    STEP(4, 5)
    STEP(5, 6)
    STEP(6, 7)
    STEP(7, cs)
#undef PREF
#undef TCORE
#undef STEP
}

// ---------------- per-iteration: link aggregate + link GRU + lxk ----------------
// One wave per link; two lanes split each 32-B record (coalesced 16-B halves),
// v_dot2_f32_bf16 unpack-accumulate, dim-splitting butterfly reduce.
__global__ __launch_bounds__(256) void k_links(
    const unsigned int* __restrict__ p2lp, const unsigned short* __restrict__ seq,
    const float* __restrict__ lk, const float* __restrict__ lrk,
    const float* __restrict__ lb,
    const float* __restrict__ pk, const float* __restrict__ pb,
    float* ls, unsigned short* __restrict__ lxk)
{
    int lane = threadIdx.x & 63;
    int l = blockIdx.x * 4 + (threadIdx.x >> 6);
    size_t base = (size_t)l * MAX_PL;
    int half = lane & 1;
    int r0 = lane >> 1;

    unsigned int e0 = p2lp[base + r0];
    unsigned int e1 = p2lp[base + r0 + 32];
    unsigned int e2 = p2lp[base + r0 + 64];

    const unsigned short* sh = seq + half * 8;
    unsigned int pi, si;
    pi = e0 & 0x3FFFFu; si = e0 >> 18;
    uint4 a0 = *(const uint4*)(sh + ((size_t)si * N_PATHS + pi) * DIM);
    pi = e1 & 0x3FFFFu; si = e1 >> 18;
    uint4 a1 = *(const uint4*)(sh + ((size_t)si * N_PATHS + pi) * DIM);
    pi = e2 & 0x3FFFFu; si = e2 >> 18;
    uint4 a2 = *(const uint4*)(sh + ((size_t)si * N_PATHS + pi) * DIM);

    float acc[8];
    #pragma unroll
    for (int i = 0; i < 8; i++) acc[i] = 0.0f;
    unsigned int selLo = 0x00003F80u;   // bf16 (lo=1.0, hi=0)
    unsigned int selHi = 0x3F800000u;   // bf16 (lo=0, hi=1.0)

#define DOTU(u, i0) \
    asm("v_dot2_f32_bf16 %0, %1, %2, %0" : "+v"(acc[i0]) : "v"(u), "v"(selLo)); \
    asm("v_dot2_f32_bf16 %0, %1, %2, %0" : "+v"(acc[i0 + 1]) : "v"(u), "v"(selHi));
#define DOT8(a) DOTU(a.x, 0) DOTU(a.y, 2) DOTU(a.z, 4) DOTU(a.w, 6)

    DOT8(a0) DOT8(a1) DOT8(a2)
    if (r0 < 4) {
        unsigned int e3 = p2lp[base + r0 + 96];
        pi = e3 & 0x3FFFFu; si = e3 >> 18;
        uint4 a3 = *(const uint4*)(sh + ((size_t)si * N_PATHS + pi) * DIM);
        DOT8(a3)
    }
#undef DOTU
#undef DOT8

    // dim-splitting butterfly: lane ends with sum of one dim
    float v4[4];
    {
        int sel = (lane & 2) ? 4 : 0;
        #pragma unroll
        for (int i = 0; i < 4; i++)
            v4[i] = acc[sel + i] + __shfl_xor(acc[(4 - sel) + i], 2);
    }
    float v2[2];
    {
        int sel = (lane & 4) ? 2 : 0;
        #pragma unroll
        for (int i = 0; i < 2; i++)
            v2[i] = v4[sel + i] + __shfl_xor(v4[(2 - sel) + i], 4);
    }
    float s;
    {
        int sel = (lane & 8) ? 1 : 0;
        s = v2[sel] + __shfl_xor(v2[1 - sel], 8);
    }
    s += __shfl_xor(s, 16);
    s += __shfl_xor(s, 32);
    // lane holds dim = (lane&1)*8 + ((lane>>1)&1)*4 + ((lane>>2)&1)*2 + ((lane>>3)&1)

    float accf[16];
    #pragma unroll
    for (int k = 0; k < 16; k++) {
        int src = ((k >> 3) & 1) | (((k >> 2) & 1) << 1) | (((k >> 1) & 1) << 2) | ((k & 1) << 3);
        accf[k] = __shfl(s, src);
    }

    float h[DIM];
    #pragma unroll
    for (int d = 0; d < DIM; d++) h[d] = ls[(size_t)l * DIM + d];

    int j = (lane < 48) ? lane : 0;
    float mx = lb[j];
    float mi = lb[48 + j];
    #pragma unroll
    for (int k = 0; k < DIM; k++) {
        mx = fmaf(accf[k], lk[k * 48 + j], mx);
        mi = fmaf(h[k],   lrk[k * 48 + j], mi);
    }

    int d = lane & 15;
    float xz = __shfl(mx, d),      rz = __shfl(mi, d);
    float xr = __shfl(mx, d + 16), rr = __shfl(mi, d + 16);
    float xh = __shfl(mx, d + 32), rh = __shfl(mi, d + 32);
    float z  = fast_sigmoid(xz + rz);
    float r  = fast_sigmoid(xr + rr);
    float hh = fast_tanh(xh + r * rh);
    float hn = z * h[d] + (1.0f - z) * hh;

    if (lane < DIM) ls[(size_t)l * DIM + lane] = hn;

    float hf[DIM];
    #pragma unroll
    for (int k = 0; k < DIM; k++) hf[k] = __shfl(hn, k);
    if (lane < 48) {
        float a = pb[lane];
        #pragma unroll
        for (int k = 0; k < DIM; k++) a = fmaf(hf[k], pk[k * 48 + lane], a);
        lxk[(size_t)l * 48 + lane] = (unsigned short)(pk_bf16(a, a) & 0xffffu);
    }
}

// ---------------- readout ----------------
__global__ __launch_bounds__(256) void k_readout(
    const unsigned short* __restrict__ seq, const int* __restrict__ l2p,
    const float* __restrict__ cap,
    const float* __restrict__ w1, const float* __restrict__ b1,
    const float* __restrict__ w2, const float* __restrict__ b2,
    const float* __restrict__ w3, const float* __restrict__ b3,
    float* __restrict__ out)
{
    int p = blockIdx.x * blockDim.x + threadIdx.x;
    if (p >= N_PATHS) return;
    float delay = 0.0f;
    for (int t = 1; t <= PATH_LEN; t++) {
        const uint4* gp = (const uint4*)(seq + ((size_t)t * N_PATHS + p) * DIM);
        uint4 a = gp[0], c = gp[1];
        float h[DIM];
        h[0]  = bflo(a.x); h[1]  = bfhi(a.x); h[2]  = bflo(a.y); h[3]  = bfhi(a.y);
        h[4]  = bflo(a.z); h[5]  = bfhi(a.z); h[6]  = bflo(a.w); h[7]  = bfhi(a.w);
        h[8]  = bflo(c.x); h[9]  = bfhi(c.x); h[10] = bflo(c.y); h[11] = bfhi(c.y);
        h[12] = bflo(c.z); h[13] = bfhi(c.z); h[14] = bflo(c.w); h[15] = bfhi(c.w);

        float h1[8];
        #pragma unroll
        for (int jj = 0; jj < 8; jj++) {
            float a1 = b1[jj];
            #pragma unroll
            for (int k = 0; k < DIM; k++) a1 = fmaf(h[k], w1[k * 8 + jj], a1);
            h1[jj] = fmaxf(a1, 0.0f);
        }
        float h2[4];
        #pragma unroll
        for (int jj = 0; jj < 4; jj++) {
            float a2 = b2[jj];
            #pragma unroll
            for (int k = 0; k < 8; k++) a2 = fmaf(h1[k], w2[k * 4 + jj], a2);
            h2[jj] = fmaxf(a2, 0.0f);
        }
        float o = b3[0];
        #pragma unroll
        for (int k = 0; k < 4; k++) o = fmaf(h2[k], w3[k], o);
        o = softplusf_(o);

        float cp = cap[l2p[(size_t)p * PATH_LEN + (t - 1)]];
        delay += o / cp;
    }
    out[p] = delay;
}

extern "C" void kernel_launch(void* const* d_in, const int* in_sizes, int n_in,
                              void* d_out, int out_size, void* d_ws, size_t ws_size,
                              hipStream_t stream)
{
    const float* flow_traffic = (const float*)d_in[0];
    const float* flow_packets = (const float*)d_in[1];
    const float* flow_pktsize = (const float*)d_in[2];
    const float* flow_type    = (const float*)d_in[3];
    const float* link_cap     = (const float*)d_in[4];
    const int*   l2p          = (const int*)d_in[5];
    const int*   p2l          = (const int*)d_in[6];
    const float* fe_w1 = (const float*)d_in[7];
    const float* fe_b1 = (const float*)d_in[8];
    const float* fe_w2 = (const float*)d_in[9];
    const float* fe_b2 = (const float*)d_in[10];
    const float* le_w1 = (const float*)d_in[11];
    const float* le_b1 = (const float*)d_in[12];
    const float* le_w2 = (const float*)d_in[13];
    const float* le_b2 = (const float*)d_in[14];
    const float* pgru_k  = (const float*)d_in[15];
    const float* pgru_rk = (const float*)d_in[16];
    const float* pgru_b  = (const float*)d_in[17];
    const float* lgru_k  = (const float*)d_in[18];
    const float* lgru_rk = (const float*)d_in[19];
    const float* lgru_b  = (const float*)d_in[20];
    const float* ro_w1 = (const float*)d_in[21];
    const float* ro_b1 = (const float*)d_in[22];
    const float* ro_w2 = (const float*)d_in[23];
    const float* ro_b2 = (const float*)d_in[24];
    const float* ro_w3 = (const float*)d_in[25];
    const float* ro_b3 = (const float*)d_in[26];
    float* out = (float*)d_out;

    char* ws = (char*)d_ws;
    unsigned short* seq   = (unsigned short*)ws;
    float*          ls    = (float*)(ws + SEQ_BYTES);
    unsigned short* lxk   = (unsigned short*)(ws + SEQ_BYTES + LS_BYTES);
    unsigned int*   p2lpE = (unsigned int*)(ws + SEQ_BYTES + LS_BYTES + LXK_BYTES);
    unsigned int*   p2lpO = (unsigned int*)(ws + SEQ_BYTES + LS_BYTES + LXK_BYTES + P2L_BYTES);

    k_pack<<<(N_LINKS * MAX_PL + 255) / 256, 256, 0, stream>>>(p2l, p2lpE, p2lpO);
    k_init_links<<<N_LINKS, 64, 0, stream>>>(flow_traffic, link_cap, p2l,
        le_w1, le_b1, le_w2, le_b2, pgru_k, pgru_b, ls, lxk);
    k_init_paths<<<(N_PATHS + 255) / 256, 256, 0, stream>>>(flow_traffic,
        flow_packets, flow_pktsize, flow_type, fe_w1, fe_b1, fe_w2, fe_b2, seq);

    int nPathBlocks = (N_PATHS / 32 + 3) / 4;   // 1563 blocks of 4 waves
    for (int it = 0; it < ITERS; ++it) {
        int ps = (it & 1) ? 9 : 8;
        int cs = (it & 1) ? 8 : 9;
        k_paths<<<nPathBlocks, 256, 0, stream>>>(l2p, lxk, pgru_rk, pgru_b,
            seq, ps, cs);
        if (it != ITERS - 1)   // final link GRU is dead: output uses only seq
            k_links<<<N_LINKS / 4, 256, 0, stream>>>((it & 1) ? p2lpO : p2lpE,
                seq, lgru_k, lgru_rk, lgru_b, pgru_k, pgru_b, ls, lxk);
    }

    k_readout<<<(N_PATHS + 255) / 256, 256, 0, stream>>>(seq, l2p, link_cap,
        ro_w1, ro_b1, ro_w2, ro_b2, ro_w3, ro_b3, out);
}

// Round 6
// 637.625 us; speedup vs baseline: 1.0010x; 1.0010x over previous
//
#include <hip/hip_runtime.h>
#include <hip/hip_bf16.h>
#include <math.h>

#define N_PATHS  200000
#define PATH_LEN 8
#define N_LINKS  20000
#define MAX_PL   100
#define DIM      16
#define ITERS    8

typedef __attribute__((ext_vector_type(8))) short bf16x8;
typedef __attribute__((ext_vector_type(4))) float f32x4;
typedef __attribute__((ext_vector_type(2))) float f32x2;

// ws layout (bytes):
//   seq   : ushort[10][N_PATHS][16] = 64,000,000  (bf16 states; slots 1..7 = steps, 8/9 = prev/cur rotation)
//   ls    : float [N_LINKS][16]     =  1,280,000
//   lxk   : float [N_LINKS][48]     =  3,840,000  (fp32: link_state @ pgru_k + pgru_b[0])
//   p2lpE : uint  [N_LINKS*MAX_PL]  =  8,000,000
//   p2lpO : uint  [N_LINKS*MAX_PL]  =  8,000,000
#define SEQ_BYTES 64000000ull
#define LS_BYTES  1280000ull
#define LXK_BYTES 3840000ull
#define P2L_BYTES 8000000ull
#define SLOT_BYTES 6400000u   // N_PATHS * 16 * 2

__device__ __forceinline__ float fast_sigmoid(float x) {
    return __builtin_amdgcn_rcpf(1.0f + __expf(-x));
}
__device__ __forceinline__ float fast_tanh(float x) {
    float ax = fabsf(x);
    float t  = __expf(-2.0f * ax);
    float r  = (1.0f - t) * __builtin_amdgcn_rcpf(1.0f + t);
    return copysignf(r, x);
}
__device__ __forceinline__ float softplusf_(float x) {
    return fmaxf(x, 0.0f) + log1pf(expf(-fabsf(x)));
}
__device__ __forceinline__ float bflo(unsigned int u) {
    union { unsigned int i; float f; } c; c.i = u << 16; return c.f;
}
__device__ __forceinline__ float bfhi(unsigned int u) {
    union { unsigned int i; float f; } c; c.i = u & 0xffff0000u; return c.f;
}
__device__ __forceinline__ unsigned int pk_bf16(float lo, float hi) {
    unsigned int r;
    asm("v_cvt_pk_bf16_f32 %0, %1, %2" : "=v"(r) : "v"(lo), "v"(hi));
    return r;
}

// packed f32 math (VOP3P, gfx90a+)
__device__ __forceinline__ f32x2 pk_add2(f32x2 a, f32x2 b) {
    f32x2 d; asm("v_pk_add_f32 %0, %1, %2" : "=v"(d) : "v"(a), "v"(b)); return d;
}
__device__ __forceinline__ f32x2 pk_mul2(f32x2 a, f32x2 b) {
    f32x2 d; asm("v_pk_mul_f32 %0, %1, %2" : "=v"(d) : "v"(a), "v"(b)); return d;
}
__device__ __forceinline__ f32x2 pk_fma2(f32x2 a, f32x2 b, f32x2 c) {
    f32x2 d; asm("v_pk_fma_f32 %0, %1, %2, %3" : "=v"(d) : "v"(a), "v"(b), "v"(c)); return d;
}
__device__ __forceinline__ f32x2 mk2(float a, float b) { f32x2 r; r.x = a; r.y = b; return r; }

// pairwise sigmoid: rcp(1 + exp2(-log2e * x))
__device__ __forceinline__ f32x2 sig2(f32x2 x) {
    f32x2 t = pk_mul2(x, mk2(-1.44269504f, -1.44269504f));
    f32x2 e; e.x = __builtin_amdgcn_exp2f(t.x); e.y = __builtin_amdgcn_exp2f(t.y);
    f32x2 d = pk_add2(e, mk2(1.0f, 1.0f));
    f32x2 r; r.x = __builtin_amdgcn_rcpf(d.x); r.y = __builtin_amdgcn_rcpf(d.y);
    return r;
}
// pairwise tanh: 1 - 2*rcp(1 + exp2(2*log2e * x))
__device__ __forceinline__ f32x2 tanh2(f32x2 x) {
    f32x2 t = pk_mul2(x, mk2(2.88539008f, 2.88539008f));
    f32x2 e; e.x = __builtin_amdgcn_exp2f(t.x); e.y = __builtin_amdgcn_exp2f(t.y);
    f32x2 d = pk_add2(e, mk2(1.0f, 1.0f));
    f32x2 r; r.x = __builtin_amdgcn_rcpf(d.x); r.y = __builtin_amdgcn_rcpf(d.y);
    return pk_fma2(r, mk2(-2.0f, -2.0f), mk2(1.0f, 1.0f));
}

union U8 { unsigned int u[4]; bf16x8 v; };

// ---------------- pack p2l into two slot-resolved variants ----------------
__global__ __launch_bounds__(256) void k_pack(const int* __restrict__ p2l,
                                              unsigned int* __restrict__ outE,
                                              unsigned int* __restrict__ outO)
{
    int i = blockIdx.x * 256 + threadIdx.x;
    if (i < N_LINKS * MAX_PL) {
        unsigned int pi = (unsigned int)p2l[2 * i];
        unsigned int si = (unsigned int)p2l[2 * i + 1];
        unsigned int sE = (si == 0) ? 8u : ((si == 8) ? 9u : si);
        unsigned int sO = (si == 0) ? 9u : ((si == 8) ? 8u : si);
        outE[i] = (sE << 18) | pi;
        outO[i] = (sO << 18) | pi;
    }
}

// ---------------- init: link load -> link_state -> lxk (fp32) ----------------
__global__ __launch_bounds__(64) void k_init_links(
    const float* __restrict__ traffic, const float* __restrict__ cap,
    const int* __restrict__ p2l,
    const float* __restrict__ le_w1, const float* __restrict__ le_b1,
    const float* __restrict__ le_w2, const float* __restrict__ le_b2,
    const float* __restrict__ pk, const float* __restrict__ pb,
    float* __restrict__ ls, float* __restrict__ lxk)
{
    int l = blockIdx.x;
    int lane = threadIdx.x;
    float s = 0.0f;
    for (int j = lane; j < MAX_PL; j += 64) {
        int p = p2l[(size_t)(l * MAX_PL + j) * 2 + 0];
        s += traffic[p];
    }
    #pragma unroll
    for (int off = 32; off > 0; off >>= 1) s += __shfl_xor(s, off);

    float c = cap[l];
    float f0 = c * 0.1f;
    float f1 = s / (c * 1e9f);

    float h1[DIM];
    #pragma unroll
    for (int d = 0; d < DIM; d++)
        h1[d] = fmaxf(f0 * le_w1[d] + f1 * le_w1[DIM + d] + le_b1[d], 0.0f);

    float h2[DIM];
    #pragma unroll
    for (int d = 0; d < DIM; d++) {
        float a = le_b2[d];
        #pragma unroll
        for (int k = 0; k < DIM; k++) a = fmaf(h1[k], le_w2[k * DIM + d], a);
        h2[d] = fmaxf(a, 0.0f);
    }
    if (lane < DIM) ls[(size_t)l * DIM + lane] = h2[lane];
    if (lane < 48) {
        float a = pb[lane];
        #pragma unroll
        for (int k = 0; k < DIM; k++) a = fmaf(h2[k], pk[k * 48 + lane], a);
        lxk[(size_t)l * 48 + lane] = a;
    }
}

// ---------------- init: path_state -> seq slot 8 (bf16) ----------------
__global__ __launch_bounds__(256) void k_init_paths(
    const float* __restrict__ traffic, const float* __restrict__ packets,
    const float* __restrict__ pktsize, const float* __restrict__ ftype,
    const float* __restrict__ fe_w1, const float* __restrict__ fe_b1,
    const float* __restrict__ fe_w2, const float* __restrict__ fe_b2,
    unsigned short* __restrict__ seq)
{
    int p = blockIdx.x * blockDim.x + threadIdx.x;
    if (p >= N_PATHS) return;
    float f[5];
    f[0] = traffic[p] * 0.0001f;
    f[1] = packets[p] * 0.01f;
    f[2] = pktsize[p] * 0.001f;
    f[3] = ftype[p * 2 + 0];
    f[4] = ftype[p * 2 + 1];

    float h1[DIM];
    #pragma unroll
    for (int d = 0; d < DIM; d++) {
        float a = fe_b1[d];
        #pragma unroll
        for (int k = 0; k < 5; k++) a = fmaf(f[k], fe_w1[k * DIM + d], a);
        h1[d] = fmaxf(a, 0.0f);
    }
    float h2[DIM];
    #pragma unroll
    for (int d = 0; d < DIM; d++) {
        float a = fe_b2[d];
        #pragma unroll
        for (int k = 0; k < DIM; k++) a = fmaf(h1[k], fe_w2[k * DIM + d], a);
        h2[d] = fmaxf(a, 0.0f);
    }
    unsigned int pkd[8];
    #pragma unroll
    for (int q = 0; q < 8; q++) pkd[q] = pk_bf16(h2[2 * q], h2[2 * q + 1]);
    uint4* out = (uint4*)(seq + ((size_t)8 * N_PATHS + p) * DIM);
    out[0] = make_uint4(pkd[0], pkd[1], pkd[2], pkd[3]);
    out[1] = make_uint4(pkd[4], pkd[5], pkd[6], pkd[7]);
}

// ---------------- per-iteration: path GRU via MFMA, 16 paths/wave ----------------
// D/C layout (16x16x32_bf16): col=lane&15, row=(lane>>4)*4+reg.
// A/B split-K hedge: weights*0.5 duplicated in both halves, h in both B halves.
// fp32 lxk (no unpack), 32-bit offsets, packed-f32 gate math, rolling prefetch 4.
__global__ __launch_bounds__(256, 4) void k_paths(
    const int* __restrict__ l2p, const float* __restrict__ lxk,
    const float* __restrict__ rk, const float* __restrict__ b,
    unsigned short* __restrict__ seq, int ps, int cs)
{
    int l = threadIdx.x & 63;
    int wave = (blockIdx.x * 256 + threadIdx.x) >> 6;   // 0..12499 exact
    int pr = l & 15;
    int g  = l >> 4;
    int kq = g * 4;
    int p  = wave * 16 + pr;

    U8 Az, Ar, Ah;
    {
        #pragma unroll
        for (int i = 0; i < 2; i++) {
            float wz0 = rk[(kq + 2 * i) * 48 + pr] * 0.5f;
            float wz1 = rk[(kq + 2 * i + 1) * 48 + pr] * 0.5f;
            float wr0 = rk[(kq + 2 * i) * 48 + 16 + pr] * 0.5f;
            float wr1 = rk[(kq + 2 * i + 1) * 48 + 16 + pr] * 0.5f;
            float wh0 = rk[(kq + 2 * i) * 48 + 32 + pr] * 0.5f;
            float wh1 = rk[(kq + 2 * i + 1) * 48 + 32 + pr] * 0.5f;
            Az.u[i] = pk_bf16(wz0, wz1); Az.u[i + 2] = Az.u[i];
            Ar.u[i] = pk_bf16(wr0, wr1); Ar.u[i + 2] = Ar.u[i];
            Ah.u[i] = pk_bf16(wh0, wh1); Ah.u[i + 2] = Ah.u[i];
        }
    }
    f32x4 Cz, Cr, Ch;
    #pragma unroll
    for (int r = 0; r < 4; r++) {
        Cz[r] = b[48 + kq + r];
        Cr[r] = b[48 + 16 + kq + r];
        Ch[r] = b[48 + 32 + kq + r];
    }

    // full l2p row per lane (quad-duplicated loads -> broadcast)
    int4 ia = *(const int4*)(l2p + (size_t)p * 8);
    int4 ib = *(const int4*)(l2p + (size_t)p * 8 + 4);
#define IDX(t) ((t) == 0 ? ia.x : (t) == 1 ? ia.y : (t) == 2 ? ia.z : (t) == 3 ? ia.w : \
                (t) == 4 ? ib.x : (t) == 5 ? ib.y : (t) == 6 ? ib.z : ib.w)

    const char* lxkc = (const char*)lxk;
    char* seqc = (char*)seq;
    unsigned gsh = (unsigned)(g * 16);
    unsigned sbase = (unsigned)p * 32u + (unsigned)(g * 8);
    unsigned csoff = (unsigned)cs * SLOT_BYTES + sbase;

    float4 pz[8], prr[8], ph[8];
#define PREF(t) { \
    unsigned off = (unsigned)IDX(t) * 192u + gsh; \
    const char* xp = lxkc + off; \
    pz[t]  = *(const float4*)(xp); \
    prr[t] = *(const float4*)(xp + 64); \
    ph[t]  = *(const float4*)(xp + 128); }

    PREF(0) PREF(1) PREF(2) PREF(3)

    f32x2 hA, hB;
    U8 B;
    {
        uint2 hp = *(const uint2*)(seqc + ((unsigned)ps * SLOT_BYTES + sbase));
        hA = mk2(bflo(hp.x), bfhi(hp.x));
        hB = mk2(bflo(hp.y), bfhi(hp.y));
        B.u[0] = hp.x; B.u[1] = hp.y; B.u[2] = hp.x; B.u[3] = hp.y;
    }

#define STEPX(t, soff) { \
    f32x4 az = __builtin_amdgcn_mfma_f32_16x16x32_bf16(Az.v, B.v, Cz, 0, 0, 0); \
    f32x4 ar = __builtin_amdgcn_mfma_f32_16x16x32_bf16(Ar.v, B.v, Cr, 0, 0, 0); \
    f32x4 ah = __builtin_amdgcn_mfma_f32_16x16x32_bf16(Ah.v, B.v, Ch, 0, 0, 0); \
    f32x2 zA = sig2(pk_add2(mk2(pz[t].x, pz[t].y), mk2(az[0], az[1]))); \
    f32x2 zB = sig2(pk_add2(mk2(pz[t].z, pz[t].w), mk2(az[2], az[3]))); \
    f32x2 rA = sig2(pk_add2(mk2(prr[t].x, prr[t].y), mk2(ar[0], ar[1]))); \
    f32x2 rB = sig2(pk_add2(mk2(prr[t].z, prr[t].w), mk2(ar[2], ar[3]))); \
    f32x2 qA = tanh2(pk_fma2(rA, mk2(ah[0], ah[1]), mk2(ph[t].x, ph[t].y))); \
    f32x2 qB = tanh2(pk_fma2(rB, mk2(ah[2], ah[3]), mk2(ph[t].z, ph[t].w))); \
    f32x2 dA = pk_fma2(qA, mk2(-1.0f, -1.0f), hA); \
    f32x2 dB = pk_fma2(qB, mk2(-1.0f, -1.0f), hB); \
    hA = pk_fma2(zA, dA, qA); \
    hB = pk_fma2(zB, dB, qB); \
    unsigned int p01 = pk_bf16(hA.x, hA.y); \
    unsigned int p23 = pk_bf16(hB.x, hB.y); \
    *(uint2*)(seqc + (soff)) = make_uint2(p01, p23); \
    B.u[0] = p01; B.u[1] = p23; B.u[2] = p01; B.u[3] = p23; }

    STEPX(0, 1u * SLOT_BYTES + sbase)  PREF(4)
    STEPX(1, 2u * SLOT_BYTES + sbase)  PREF(5)
    STEPX(2, 3u * SLOT_BYTES + sbase)  PREF(6)
    STEPX(3, 4u * SLOT_BYTES + sbase)  PREF(7)
    STEPX(4, 5u * SLOT_BYTES + sbase)
    STEPX(5, 6u * SLOT_BYTES + sbase)
    STEPX(6, 7u * SLOT_BYTES + sbase)
    STEPX(7, csoff)
#undef PREF
#undef STEPX
#undef IDX
}

// ---------------- per-iteration: link aggregate + link GRU + lxk ----------------
__global__ __launch_bounds__(256) void k_links(
    const unsigned int* __restrict__ p2lp, const unsigned short* __restrict__ seq,
    const float* __restrict__ lk, const float* __restrict__ lrk,
    const float* __restrict__ lb,
    const float* __restrict__ pk, const float* __restrict__ pb,
    float* ls, float* __restrict__ lxk)
{
    int lane = threadIdx.x & 63;
    int l = blockIdx.x * 4 + (threadIdx.x >> 6);
    size_t base = (size_t)l * MAX_PL;
    int half = lane & 1;
    int r0 = lane >> 1;

    unsigned int e0 = p2lp[base + r0];
    unsigned int e1 = p2lp[base + r0 + 32];
    unsigned int e2 = p2lp[base + r0 + 64];

    const unsigned short* sh = seq + half * 8;
    unsigned int pi, si;
    pi = e0 & 0x3FFFFu; si = e0 >> 18;
    uint4 a0 = *(const uint4*)(sh + ((size_t)si * N_PATHS + pi) * DIM);
    pi = e1 & 0x3FFFFu; si = e1 >> 18;
    uint4 a1 = *(const uint4*)(sh + ((size_t)si * N_PATHS + pi) * DIM);
    pi = e2 & 0x3FFFFu; si = e2 >> 18;
    uint4 a2 = *(const uint4*)(sh + ((size_t)si * N_PATHS + pi) * DIM);

    float acc[8];
    #pragma unroll
    for (int i = 0; i < 8; i++) acc[i] = 0.0f;
    unsigned int selLo = 0x00003F80u;
    unsigned int selHi = 0x3F800000u;

#define DOTU(u, i0) \
    asm("v_dot2_f32_bf16 %0, %1, %2, %0" : "+v"(acc[i0]) : "v"(u), "v"(selLo)); \
    asm("v_dot2_f32_bf16 %0, %1, %2, %0" : "+v"(acc[i0 + 1]) : "v"(u), "v"(selHi));
#define DOT8(a) DOTU(a.x, 0) DOTU(a.y, 2) DOTU(a.z, 4) DOTU(a.w, 6)

    DOT8(a0) DOT8(a1) DOT8(a2)
    if (r0 < 4) {
        unsigned int e3 = p2lp[base + r0 + 96];
        pi = e3 & 0x3FFFFu; si = e3 >> 18;
        uint4 a3 = *(const uint4*)(sh + ((size_t)si * N_PATHS + pi) * DIM);
        DOT8(a3)
    }
#undef DOTU
#undef DOT8

    float v4[4];
    {
        int sel = (lane & 2) ? 4 : 0;
        #pragma unroll
        for (int i = 0; i < 4; i++)
            v4[i] = acc[sel + i] + __shfl_xor(acc[(4 - sel) + i], 2);
    }
    float v2[2];
    {
        int sel = (lane & 4) ? 2 : 0;
        #pragma unroll
        for (int i = 0; i < 2; i++)
            v2[i] = v4[sel + i] + __shfl_xor(v4[(2 - sel) + i], 4);
    }
    float s;
    {
        int sel = (lane & 8) ? 1 : 0;
        s = v2[sel] + __shfl_xor(v2[1 - sel], 8);
    }
    s += __shfl_xor(s, 16);
    s += __shfl_xor(s, 32);

    float accf[16];
    #pragma unroll
    for (int k = 0; k < 16; k++) {
        int src = ((k >> 3) & 1) | (((k >> 2) & 1) << 1) | (((k >> 1) & 1) << 2) | ((k & 1) << 3);
        accf[k] = __shfl(s, src);
    }

    float h[DIM];
    #pragma unroll
    for (int d = 0; d < DIM; d++) h[d] = ls[(size_t)l * DIM + d];

    int j = (lane < 48) ? lane : 0;
    float mx = lb[j];
    float mi = lb[48 + j];
    #pragma unroll
    for (int k = 0; k < DIM; k++) {
        mx = fmaf(accf[k], lk[k * 48 + j], mx);
        mi = fmaf(h[k],   lrk[k * 48 + j], mi);
    }

    int d = lane & 15;
    float xz = __shfl(mx, d),      rz = __shfl(mi, d);
    float xr = __shfl(mx, d + 16), rr = __shfl(mi, d + 16);
    float xh = __shfl(mx, d + 32), rh = __shfl(mi, d + 32);
    float z  = fast_sigmoid(xz + rz);
    float r  = fast_sigmoid(xr + rr);
    float hh = fast_tanh(xh + r * rh);
    float hn = z * h[d] + (1.0f - z) * hh;

    if (lane < DIM) ls[(size_t)l * DIM + lane] = hn;

    float hf[DIM];
    #pragma unroll
    for (int k = 0; k < DIM; k++) hf[k] = __shfl(hn, k);
    if (lane < 48) {
        float a = pb[lane];
        #pragma unroll
        for (int k = 0; k < DIM; k++) a = fmaf(hf[k], pk[k * 48 + lane], a);
        lxk[(size_t)l * 48 + lane] = a;
    }
}

// ---------------- readout ----------------
__global__ __launch_bounds__(256) void k_readout(
    const unsigned short* __restrict__ seq, const int* __restrict__ l2p,
    const float* __restrict__ cap,
    const float* __restrict__ w1, const float* __restrict__ b1,
    const float* __restrict__ w2, const float* __restrict__ b2,
    const float* __restrict__ w3, const float* __restrict__ b3,
    float* __restrict__ out)
{
    int p = blockIdx.x * blockDim.x + threadIdx.x;
    if (p >= N_PATHS) return;
    float delay = 0.0f;
    for (int t = 1; t <= PATH_LEN; t++) {
        const uint4* gp = (const uint4*)(seq + ((size_t)t * N_PATHS + p) * DIM);
        uint4 a = gp[0], c = gp[1];
        float h[DIM];
        h[0]  = bflo(a.x); h[1]  = bfhi(a.x); h[2]  = bflo(a.y); h[3]  = bfhi(a.y);
        h[4]  = bflo(a.z); h[5]  = bfhi(a.z); h[6]  = bflo(a.w); h[7]  = bfhi(a.w);
        h[8]  = bflo(c.x); h[9]  = bfhi(c.x); h[10] = bflo(c.y); h[11] = bfhi(c.y);
        h[12] = bflo(c.z); h[13] = bfhi(c.z); h[14] = bflo(c.w); h[15] = bfhi(c.w);

        float h1[8];
        #pragma unroll
        for (int jj = 0; jj < 8; jj++) {
            float a1 = b1[jj];
            #pragma unroll
            for (int k = 0; k < DIM; k++) a1 = fmaf(h[k], w1[k * 8 + jj], a1);
            h1[jj] = fmaxf(a1, 0.0f);
        }
        float h2[4];
        #pragma unroll
        for (int jj = 0; jj < 4; jj++) {
            float a2 = b2[jj];
            #pragma unroll
            for (int k = 0; k < 8; k++) a2 = fmaf(h1[k], w2[k * 4 + jj], a2);
            h2[jj] = fmaxf(a2, 0.0f);
        }
        float o = b3[0];
        #pragma unroll
        for (int k = 0; k < 4; k++) o = fmaf(h2[k], w3[k], o);
        o = softplusf_(o);

        float cp = cap[l2p[(size_t)p * PATH_LEN + (t - 1)]];
        delay += o / cp;
    }
    out[p] = delay;
}

extern "C" void kernel_launch(void* const* d_in, const int* in_sizes, int n_in,
                              void* d_out, int out_size, void* d_ws, size_t ws_size,
                              hipStream_t stream)
{
    const float* flow_traffic = (const float*)d_in[0];
    const float* flow_packets = (const float*)d_in[1];
    const float* flow_pktsize = (const float*)d_in[2];
    const float* flow_type    = (const float*)d_in[3];
    const float* link_cap     = (const float*)d_in[4];
    const int*   l2p          = (const int*)d_in[5];
    const int*   p2l          = (const int*)d_in[6];
    const float* fe_w1 = (const float*)d_in[7];
    const float* fe_b1 = (const float*)d_in[8];
    const float* fe_w2 = (const float*)d_in[9];
    const float* fe_b2 = (const float*)d_in[10];
    const float* le_w1 = (const float*)d_in[11];
    const float* le_b1 = (const float*)d_in[12];
    const float* le_w2 = (const float*)d_in[13];
    const float* le_b2 = (const float*)d_in[14];
    const float* pgru_k  = (const float*)d_in[15];
    const float* pgru_rk = (const float*)d_in[16];
    const float* pgru_b  = (const float*)d_in[17];
    const float* lgru_k  = (const float*)d_in[18];
    const float* lgru_rk = (const float*)d_in[19];
    const float* lgru_b  = (const float*)d_in[20];
    const float* ro_w1 = (const float*)d_in[21];
    const float* ro_b1 = (const float*)d_in[22];
    const float* ro_w2 = (const float*)d_in[23];
    const float* ro_b2 = (const float*)d_in[24];
    const float* ro_w3 = (const float*)d_in[25];
    const float* ro_b3 = (const float*)d_in[26];
    float* out = (float*)d_out;

    char* ws = (char*)d_ws;
    unsigned short* seq   = (unsigned short*)ws;
    float*          ls    = (float*)(ws + SEQ_BYTES);
    float*          lxk   = (float*)(ws + SEQ_BYTES + LS_BYTES);
    unsigned int*   p2lpE = (unsigned int*)(ws + SEQ_BYTES + LS_BYTES + LXK_BYTES);
    unsigned int*   p2lpO = (unsigned int*)(ws + SEQ_BYTES + LS_BYTES + LXK_BYTES + P2L_BYTES);

    k_pack<<<(N_LINKS * MAX_PL + 255) / 256, 256, 0, stream>>>(p2l, p2lpE, p2lpO);
    k_init_links<<<N_LINKS, 64, 0, stream>>>(flow_traffic, link_cap, p2l,
        le_w1, le_b1, le_w2, le_b2, pgru_k, pgru_b, ls, lxk);
    k_init_paths<<<(N_PATHS + 255) / 256, 256, 0, stream>>>(flow_traffic,
        flow_packets, flow_pktsize, flow_type, fe_w1, fe_b1, fe_w2, fe_b2, seq);

    for (int it = 0; it < ITERS; ++it) {
        int ps = (it & 1) ? 9 : 8;
        int cs = (it & 1) ? 8 : 9;
        k_paths<<<(N_PATHS / 16) / 4, 256, 0, stream>>>(l2p, lxk, pgru_rk,
            pgru_b, seq, ps, cs);
        if (it != ITERS - 1)   // final link GRU is dead: output uses only seq
            k_links<<<N_LINKS / 4, 256, 0, stream>>>((it & 1) ? p2lpO : p2lpE,
                seq, lgru_k, lgru_rk, lgru_b, pgru_k, pgru_b, ls, lxk);
    }

    k_readout<<<(N_PATHS + 255) / 256, 256, 0, stream>>>(seq, l2p, link_cap,
        ro_w1, ro_b1, ro_w2, ro_b2, ro_w3, ro_b3, out);
}

// Round 7
// 561.244 us; speedup vs baseline: 1.1373x; 1.1361x over previous
//
#include <hip/hip_runtime.h>
#include <hip/hip_bf16.h>
#include <math.h>

#define N_PATHS  200000
#define PATH_LEN 8
#define N_LINKS  20000
#define MAX_PL   100
#define DIM      16
#define ITERS    8

typedef __attribute__((ext_vector_type(8))) short bf16x8;
typedef __attribute__((ext_vector_type(4))) float f32x4;

// ws layout (bytes):
//   seq  : ushort[10][N_PATHS][16] = 64,000,000 (bf16 states; slots 1..7 steps, 8/9 prev/cur rotation)
//   ls   : float [N_LINKS][16]     =  1,280,000 (link_state fp32)
//   lrec : ushort[N_LINKS][32]     =  1,280,000 (64-B rec: per quad g: x[4g..4g+3] | mh[4g..4g+3])
//   p2lpE: uint  [N_LINKS*MAX_PL]  =  8,000,000
//   p2lpO: uint  [N_LINKS*MAX_PL]  =  8,000,000
#define SEQ_BYTES  64000000ull
#define LS_BYTES   1280000ull
#define LREC_BYTES 1280000ull
#define P2L_BYTES  8000000ull
#define SLOT_BYTES 6400000u   // N_PATHS * 16 * 2

__device__ __forceinline__ float fast_sigmoid(float x) {
    return __builtin_amdgcn_rcpf(1.0f + __expf(-x));
}
__device__ __forceinline__ float fast_tanh(float x) {
    float ax = fabsf(x);
    float t  = __expf(-2.0f * ax);
    float r  = (1.0f - t) * __builtin_amdgcn_rcpf(1.0f + t);
    return copysignf(r, x);
}
__device__ __forceinline__ float softplusf_(float x) {
    return fmaxf(x, 0.0f) + log1pf(expf(-fabsf(x)));
}
__device__ __forceinline__ float bflo(unsigned int u) {
    union { unsigned int i; float f; } c; c.i = u << 16; return c.f;
}
__device__ __forceinline__ float bfhi(unsigned int u) {
    union { unsigned int i; float f; } c; c.i = u & 0xffff0000u; return c.f;
}
__device__ __forceinline__ unsigned int pk_bf16(float lo, float hi) {
    unsigned int r;
    asm("v_cvt_pk_bf16_f32 %0, %1, %2" : "=v"(r) : "v"(lo), "v"(hi));
    return r;
}
__device__ __forceinline__ unsigned short bf16_1(float v) {
    return (unsigned short)(pk_bf16(v, v) & 0xffffu);
}

union U8 { unsigned int u[4]; bf16x8 v; };

// ---------------- pack p2l into two slot-resolved variants ----------------
__global__ __launch_bounds__(256) void k_pack(const int* __restrict__ p2l,
                                              unsigned int* __restrict__ outE,
                                              unsigned int* __restrict__ outO)
{
    int i = blockIdx.x * 256 + threadIdx.x;
    if (i < N_LINKS * MAX_PL) {
        unsigned int pi = (unsigned int)p2l[2 * i];
        unsigned int si = (unsigned int)p2l[2 * i + 1];
        unsigned int sE = (si == 0) ? 8u : ((si == 8) ? 9u : si);
        unsigned int sO = (si == 0) ? 9u : ((si == 8) ? 8u : si);
        outE[i] = (sE << 18) | pi;
        outO[i] = (sO << 18) | pi;
    }
}

// ---------------- init: link load -> link_state -> ls + lrec ----------------
__global__ __launch_bounds__(64) void k_init_links(
    const float* __restrict__ traffic, const float* __restrict__ cap,
    const int* __restrict__ p2l,
    const float* __restrict__ le_w1, const float* __restrict__ le_b1,
    const float* __restrict__ le_w2, const float* __restrict__ le_b2,
    const float* __restrict__ kk, const float* __restrict__ pb,
    float* __restrict__ ls, unsigned short* __restrict__ lrec)
{
    int l = blockIdx.x;
    int lane = threadIdx.x;
    float s = 0.0f;
    for (int j = lane; j < MAX_PL; j += 64) {
        int p = p2l[(size_t)(l * MAX_PL + j) * 2 + 0];
        s += traffic[p];
    }
    #pragma unroll
    for (int off = 32; off > 0; off >>= 1) s += __shfl_xor(s, off);

    float c = cap[l];
    float f0 = c * 0.1f;
    float f1 = s / (c * 1e9f);

    float h1[DIM];
    #pragma unroll
    for (int d = 0; d < DIM; d++)
        h1[d] = fmaxf(f0 * le_w1[d] + f1 * le_w1[DIM + d] + le_b1[d], 0.0f);

    float h2[DIM];
    #pragma unroll
    for (int d = 0; d < DIM; d++) {
        float a = le_b2[d];
        #pragma unroll
        for (int k = 0; k < DIM; k++) a = fmaf(h1[k], le_w2[k * DIM + d], a);
        h2[d] = fmaxf(a, 0.0f);
    }
    if (lane < DIM) ls[(size_t)l * DIM + lane] = h2[lane];
    if (lane < DIM) {
        float mh = pb[32 + lane];
        #pragma unroll
        for (int k = 0; k < DIM; k++) mh = fmaf(h2[k], kk[k * 48 + 32 + lane], mh);
        unsigned short* rec = lrec + (size_t)l * 32;
        int q = lane >> 2, idx = lane & 3;
        rec[q * 8 + idx]     = bf16_1(h2[lane]);
        rec[q * 8 + 4 + idx] = bf16_1(mh);
    }
}

// ---------------- init: path_state -> seq slot 8 (bf16) ----------------
__global__ __launch_bounds__(256) void k_init_paths(
    const float* __restrict__ traffic, const float* __restrict__ packets,
    const float* __restrict__ pktsize, const float* __restrict__ ftype,
    const float* __restrict__ fe_w1, const float* __restrict__ fe_b1,
    const float* __restrict__ fe_w2, const float* __restrict__ fe_b2,
    unsigned short* __restrict__ seq)
{
    int p = blockIdx.x * blockDim.x + threadIdx.x;
    if (p >= N_PATHS) return;
    float f[5];
    f[0] = traffic[p] * 0.0001f;
    f[1] = packets[p] * 0.01f;
    f[2] = pktsize[p] * 0.001f;
    f[3] = ftype[p * 2 + 0];
    f[4] = ftype[p * 2 + 1];

    float h1[DIM];
    #pragma unroll
    for (int d = 0; d < DIM; d++) {
        float a = fe_b1[d];
        #pragma unroll
        for (int k = 0; k < 5; k++) a = fmaf(f[k], fe_w1[k * DIM + d], a);
        h1[d] = fmaxf(a, 0.0f);
    }
    float h2[DIM];
    #pragma unroll
    for (int d = 0; d < DIM; d++) {
        float a = fe_b2[d];
        #pragma unroll
        for (int k = 0; k < DIM; k++) a = fmaf(h1[k], fe_w2[k * DIM + d], a);
        h2[d] = fmaxf(a, 0.0f);
    }
    unsigned int pkd[8];
    #pragma unroll
    for (int q = 0; q < 8; q++) pkd[q] = pk_bf16(h2[2 * q], h2[2 * q + 1]);
    uint4* out = (uint4*)(seq + ((size_t)8 * N_PATHS + p) * DIM);
    out[0] = make_uint4(pkd[0], pkd[1], pkd[2], pkd[3]);
    out[1] = make_uint4(pkd[4], pkd[5], pkd[6], pkd[7]);
}

// ---------------- per-iteration: path GRU via MFMA, 16 paths/wave ----------------
// z,r gates fold mx into the MFMA: A = [rk | k], B = [h | x], C = b0+b1.
// h gate: A = [rk_h | 0], C = b1_h; mh = x@k_h + b0_h gathered (precomputed in lrec).
// One uint4 gather per lane per step (64-B record = 1 line per path-step).
__global__ __launch_bounds__(256, 4) void k_paths(
    const int* __restrict__ l2p, const unsigned short* __restrict__ lrec,
    const float* __restrict__ rk, const float* __restrict__ kk,
    const float* __restrict__ b,
    unsigned short* __restrict__ seq, int ps, int cs)
{
    int l = threadIdx.x & 63;
    int wave = (blockIdx.x * 256 + threadIdx.x) >> 6;   // 0..12499 exact
    int pr = l & 15;
    int g  = l >> 4;
    int kq = g * 4;
    int p  = wave * 16 + pr;

    U8 Az, Ar, Ah;
    {
        #pragma unroll
        for (int i = 0; i < 2; i++) {
            int k0 = (kq + 2 * i) * 48, k1 = (kq + 2 * i + 1) * 48;
            Az.u[i]     = pk_bf16(rk[k0 + pr],      rk[k1 + pr]);
            Az.u[2 + i] = pk_bf16(kk[k0 + pr],      kk[k1 + pr]);
            Ar.u[i]     = pk_bf16(rk[k0 + 16 + pr], rk[k1 + 16 + pr]);
            Ar.u[2 + i] = pk_bf16(kk[k0 + 16 + pr], kk[k1 + 16 + pr]);
            Ah.u[i]     = pk_bf16(rk[k0 + 32 + pr], rk[k1 + 32 + pr]);
            Ah.u[2 + i] = 0;
        }
    }
    f32x4 Cz, Cr, Ch;
    #pragma unroll
    for (int r = 0; r < 4; r++) {
        Cz[r] = b[kq + r]      + b[48 + kq + r];
        Cr[r] = b[16 + kq + r] + b[64 + kq + r];
        Ch[r] = b[80 + kq + r];
    }

    int4 ia = *(const int4*)(l2p + (size_t)p * 8);
    int4 ib = *(const int4*)(l2p + (size_t)p * 8 + 4);
#define IDX(t) ((t) == 0 ? ia.x : (t) == 1 ? ia.y : (t) == 2 ? ia.z : (t) == 3 ? ia.w : \
                (t) == 4 ? ib.x : (t) == 5 ? ib.y : (t) == 6 ? ib.z : ib.w)

    const char* lrecc = (const char*)lrec;
    char* seqc = (char*)seq;
    unsigned g16 = (unsigned)(g * 16);
    unsigned sbase = (unsigned)p * 32u + (unsigned)(g * 8);
    unsigned csoff = (unsigned)cs * SLOT_BYTES + sbase;

    uint4 X[8];
    #pragma unroll
    for (int t = 0; t < 8; t++)
        X[t] = *(const uint4*)(lrecc + (unsigned)IDX(t) * 64u + g16);

    float h0, h1, h2, h3;
    U8 B;
    {
        uint2 hp = *(const uint2*)(seqc + ((unsigned)ps * SLOT_BYTES + sbase));
        h0 = bflo(hp.x); h1 = bfhi(hp.x); h2 = bflo(hp.y); h3 = bfhi(hp.y);
        B.u[0] = hp.x; B.u[1] = hp.y;
    }

#define STEPX(t, soff) { \
    B.u[2] = X[t].x; B.u[3] = X[t].y; \
    f32x4 az = __builtin_amdgcn_mfma_f32_16x16x32_bf16(Az.v, B.v, Cz, 0, 0, 0); \
    f32x4 ar = __builtin_amdgcn_mfma_f32_16x16x32_bf16(Ar.v, B.v, Cr, 0, 0, 0); \
    f32x4 ah = __builtin_amdgcn_mfma_f32_16x16x32_bf16(Ah.v, B.v, Ch, 0, 0, 0); \
    float z0 = fast_sigmoid(az[0]), z1 = fast_sigmoid(az[1]); \
    float z2 = fast_sigmoid(az[2]), z3 = fast_sigmoid(az[3]); \
    float r0 = fast_sigmoid(ar[0]), r1 = fast_sigmoid(ar[1]); \
    float r2 = fast_sigmoid(ar[2]), r3 = fast_sigmoid(ar[3]); \
    float q0 = fast_tanh(bflo(X[t].z) + r0 * ah[0]); \
    float q1 = fast_tanh(bfhi(X[t].z) + r1 * ah[1]); \
    float q2 = fast_tanh(bflo(X[t].w) + r2 * ah[2]); \
    float q3 = fast_tanh(bfhi(X[t].w) + r3 * ah[3]); \
    h0 = z0 * h0 + (1.0f - z0) * q0; \
    h1 = z1 * h1 + (1.0f - z1) * q1; \
    h2 = z2 * h2 + (1.0f - z2) * q2; \
    h3 = z3 * h3 + (1.0f - z3) * q3; \
    unsigned int p01 = pk_bf16(h0, h1), p23 = pk_bf16(h2, h3); \
    *(uint2*)(seqc + (soff)) = make_uint2(p01, p23); \
    B.u[0] = p01; B.u[1] = p23; }

    STEPX(0, 1u * SLOT_BYTES + sbase)
    STEPX(1, 2u * SLOT_BYTES + sbase)
    STEPX(2, 3u * SLOT_BYTES + sbase)
    STEPX(3, 4u * SLOT_BYTES + sbase)
    STEPX(4, 5u * SLOT_BYTES + sbase)
    STEPX(5, 6u * SLOT_BYTES + sbase)
    STEPX(6, 7u * SLOT_BYTES + sbase)
    STEPX(7, csoff)
#undef STEPX
#undef IDX
}

// ---------------- per-iteration: link aggregate + link GRU + lrec ----------------
__global__ __launch_bounds__(256) void k_links(
    const unsigned int* __restrict__ p2lp, const unsigned short* __restrict__ seq,
    const float* __restrict__ lk, const float* __restrict__ lrk,
    const float* __restrict__ lb,
    const float* __restrict__ kk, const float* __restrict__ pb,
    float* ls, unsigned short* __restrict__ lrec)
{
    int lane = threadIdx.x & 63;
    int l = blockIdx.x * 4 + (threadIdx.x >> 6);
    size_t base = (size_t)l * MAX_PL;
    int half = lane & 1;
    int r0 = lane >> 1;

    unsigned int e0 = p2lp[base + r0];
    unsigned int e1 = p2lp[base + r0 + 32];
    unsigned int e2 = p2lp[base + r0 + 64];

    const unsigned short* sh = seq + half * 8;
    unsigned int pi, si;
    pi = e0 & 0x3FFFFu; si = e0 >> 18;
    uint4 a0 = *(const uint4*)(sh + ((size_t)si * N_PATHS + pi) * DIM);
    pi = e1 & 0x3FFFFu; si = e1 >> 18;
    uint4 a1 = *(const uint4*)(sh + ((size_t)si * N_PATHS + pi) * DIM);
    pi = e2 & 0x3FFFFu; si = e2 >> 18;
    uint4 a2 = *(const uint4*)(sh + ((size_t)si * N_PATHS + pi) * DIM);

    float acc[8];
    #pragma unroll
    for (int i = 0; i < 8; i++) acc[i] = 0.0f;
    unsigned int selLo = 0x00003F80u;
    unsigned int selHi = 0x3F800000u;

#define DOTU(u, i0) \
    asm("v_dot2_f32_bf16 %0, %1, %2, %0" : "+v"(acc[i0]) : "v"(u), "v"(selLo)); \
    asm("v_dot2_f32_bf16 %0, %1, %2, %0" : "+v"(acc[i0 + 1]) : "v"(u), "v"(selHi));
#define DOT8(a) DOTU(a.x, 0) DOTU(a.y, 2) DOTU(a.z, 4) DOTU(a.w, 6)

    DOT8(a0) DOT8(a1) DOT8(a2)
    if (r0 < 4) {
        unsigned int e3 = p2lp[base + r0 + 96];
        pi = e3 & 0x3FFFFu; si = e3 >> 18;
        uint4 a3 = *(const uint4*)(sh + ((size_t)si * N_PATHS + pi) * DIM);
        DOT8(a3)
    }
#undef DOTU
#undef DOT8

    float v4[4];
    {
        int sel = (lane & 2) ? 4 : 0;
        #pragma unroll
        for (int i = 0; i < 4; i++)
            v4[i] = acc[sel + i] + __shfl_xor(acc[(4 - sel) + i], 2);
    }
    float v2[2];
    {
        int sel = (lane & 4) ? 2 : 0;
        #pragma unroll
        for (int i = 0; i < 2; i++)
            v2[i] = v4[sel + i] + __shfl_xor(v4[(2 - sel) + i], 4);
    }
    float s;
    {
        int sel = (lane & 8) ? 1 : 0;
        s = v2[sel] + __shfl_xor(v2[1 - sel], 8);
    }
    s += __shfl_xor(s, 16);
    s += __shfl_xor(s, 32);

    float accf[16];
    #pragma unroll
    for (int k = 0; k < 16; k++) {
        int src = ((k >> 3) & 1) | (((k >> 2) & 1) << 1) | (((k >> 1) & 1) << 2) | ((k & 1) << 3);
        accf[k] = __shfl(s, src);
    }

    float h[DIM];
    #pragma unroll
    for (int d = 0; d < DIM; d++) h[d] = ls[(size_t)l * DIM + d];

    int j = (lane < 48) ? lane : 0;
    float mx = lb[j];
    float mi = lb[48 + j];
    #pragma unroll
    for (int k = 0; k < DIM; k++) {
        mx = fmaf(accf[k], lk[k * 48 + j], mx);
        mi = fmaf(h[k],   lrk[k * 48 + j], mi);
    }

    int d = lane & 15;
    float xz = __shfl(mx, d),      rz = __shfl(mi, d);
    float xr = __shfl(mx, d + 16), rr = __shfl(mi, d + 16);
    float xh = __shfl(mx, d + 32), rh = __shfl(mi, d + 32);
    float z  = fast_sigmoid(xz + rz);
    float r  = fast_sigmoid(xr + rr);
    float hh = fast_tanh(xh + r * rh);
    float hn = z * h[d] + (1.0f - z) * hh;

    if (lane < DIM) ls[(size_t)l * DIM + lane] = hn;

    float hf[DIM];
    #pragma unroll
    for (int k = 0; k < DIM; k++) hf[k] = __shfl(hn, k);
    if (lane < DIM) {
        float mh = pb[32 + lane];
        #pragma unroll
        for (int k = 0; k < DIM; k++) mh = fmaf(hf[k], kk[k * 48 + 32 + lane], mh);
        unsigned short* rec = lrec + (size_t)l * 32;
        int q = lane >> 2, idx = lane & 3;
        rec[q * 8 + idx]     = bf16_1(hn);
        rec[q * 8 + 4 + idx] = bf16_1(mh);
    }
}

// ---------------- readout ----------------
__global__ __launch_bounds__(256) void k_readout(
    const unsigned short* __restrict__ seq, const int* __restrict__ l2p,
    const float* __restrict__ cap,
    const float* __restrict__ w1, const float* __restrict__ b1,
    const float* __restrict__ w2, const float* __restrict__ b2,
    const float* __restrict__ w3, const float* __restrict__ b3,
    float* __restrict__ out)
{
    int p = blockIdx.x * blockDim.x + threadIdx.x;
    if (p >= N_PATHS) return;
    float delay = 0.0f;
    for (int t = 1; t <= PATH_LEN; t++) {
        const uint4* gp = (const uint4*)(seq + ((size_t)t * N_PATHS + p) * DIM);
        uint4 a = gp[0], c = gp[1];
        float h[DIM];
        h[0]  = bflo(a.x); h[1]  = bfhi(a.x); h[2]  = bflo(a.y); h[3]  = bfhi(a.y);
        h[4]  = bflo(a.z); h[5]  = bfhi(a.z); h[6]  = bflo(a.w); h[7]  = bfhi(a.w);
        h[8]  = bflo(c.x); h[9]  = bfhi(c.x); h[10] = bflo(c.y); h[11] = bfhi(c.y);
        h[12] = bflo(c.z); h[13] = bfhi(c.z); h[14] = bflo(c.w); h[15] = bfhi(c.w);

        float h1[8];
        #pragma unroll
        for (int jj = 0; jj < 8; jj++) {
            float a1 = b1[jj];
            #pragma unroll
            for (int k = 0; k < DIM; k++) a1 = fmaf(h[k], w1[k * 8 + jj], a1);
            h1[jj] = fmaxf(a1, 0.0f);
        }
        float h2[4];
        #pragma unroll
        for (int jj = 0; jj < 4; jj++) {
            float a2 = b2[jj];
            #pragma unroll
            for (int k = 0; k < 8; k++) a2 = fmaf(h1[k], w2[k * 4 + jj], a2);
            h2[jj] = fmaxf(a2, 0.0f);
        }
        float o = b3[0];
        #pragma unroll
        for (int k = 0; k < 4; k++) o = fmaf(h2[k], w3[k], o);
        o = softplusf_(o);

        float cp = cap[l2p[(size_t)p * PATH_LEN + (t - 1)]];
        delay += o / cp;
    }
    out[p] = delay;
}

extern "C" void kernel_launch(void* const* d_in, const int* in_sizes, int n_in,
                              void* d_out, int out_size, void* d_ws, size_t ws_size,
                              hipStream_t stream)
{
    const float* flow_traffic = (const float*)d_in[0];
    const float* flow_packets = (const float*)d_in[1];
    const float* flow_pktsize = (const float*)d_in[2];
    const float* flow_type    = (const float*)d_in[3];
    const float* link_cap     = (const float*)d_in[4];
    const int*   l2p          = (const int*)d_in[5];
    const int*   p2l          = (const int*)d_in[6];
    const float* fe_w1 = (const float*)d_in[7];
    const float* fe_b1 = (const float*)d_in[8];
    const float* fe_w2 = (const float*)d_in[9];
    const float* fe_b2 = (const float*)d_in[10];
    const float* le_w1 = (const float*)d_in[11];
    const float* le_b1 = (const float*)d_in[12];
    const float* le_w2 = (const float*)d_in[13];
    const float* le_b2 = (const float*)d_in[14];
    const float* pgru_k  = (const float*)d_in[15];
    const float* pgru_rk = (const float*)d_in[16];
    const float* pgru_b  = (const float*)d_in[17];
    const float* lgru_k  = (const float*)d_in[18];
    const float* lgru_rk = (const float*)d_in[19];
    const float* lgru_b  = (const float*)d_in[20];
    const float* ro_w1 = (const float*)d_in[21];
    const float* ro_b1 = (const float*)d_in[22];
    const float* ro_w2 = (const float*)d_in[23];
    const float* ro_b2 = (const float*)d_in[24];
    const float* ro_w3 = (const float*)d_in[25];
    const float* ro_b3 = (const float*)d_in[26];
    float* out = (float*)d_out;

    char* ws = (char*)d_ws;
    unsigned short* seq   = (unsigned short*)ws;
    float*          ls    = (float*)(ws + SEQ_BYTES);
    unsigned short* lrec  = (unsigned short*)(ws + SEQ_BYTES + LS_BYTES);
    unsigned int*   p2lpE = (unsigned int*)(ws + SEQ_BYTES + LS_BYTES + LREC_BYTES);
    unsigned int*   p2lpO = (unsigned int*)(ws + SEQ_BYTES + LS_BYTES + LREC_BYTES + P2L_BYTES);

    k_pack<<<(N_LINKS * MAX_PL + 255) / 256, 256, 0, stream>>>(p2l, p2lpE, p2lpO);
    k_init_links<<<N_LINKS, 64, 0, stream>>>(flow_traffic, link_cap, p2l,
        le_w1, le_b1, le_w2, le_b2, pgru_k, pgru_b, ls, lrec);
    k_init_paths<<<(N_PATHS + 255) / 256, 256, 0, stream>>>(flow_traffic,
        flow_packets, flow_pktsize, flow_type, fe_w1, fe_b1, fe_w2, fe_b2, seq);

    for (int it = 0; it < ITERS; ++it) {
        int ps = (it & 1) ? 9 : 8;
        int cs = (it & 1) ? 8 : 9;
        k_paths<<<(N_PATHS / 16) / 4, 256, 0, stream>>>(l2p, lrec, pgru_rk,
            pgru_k, pgru_b, seq, ps, cs);
        if (it != ITERS - 1)   // final link GRU is dead: output uses only seq
            k_links<<<N_LINKS / 4, 256, 0, stream>>>((it & 1) ? p2lpO : p2lpE,
                seq, lgru_k, lgru_rk, lgru_b, pgru_k, pgru_b, ls, lrec);
    }

    k_readout<<<(N_PATHS + 255) / 256, 256, 0, stream>>>(seq, l2p, link_cap,
        ro_w1, ro_b1, ro_w2, ro_b2, ro_w3, ro_b3, out);
}